// Round 1
// baseline (365.272 us; speedup 1.0000x reference)
//
#include <hip/hip_runtime.h>
#include <stdint.h>

// irreps linear: out[v,i] = (1/64) * sum_u x[u,i] * w[u,v], 4 paths,
// mul=4096, D in {1,3,5,7}. Weights = 256 MiB read once => HBM roofline ~43us.
//
// R4 -> R5 theory: old kernel read 256B-per-row-visit at 16KiB power-of-2
// stride (64-col slice of a 4096-wide matrix) -> address-hash aliasing
// throttles per-CU bandwidth (~750 GB/s chip-wide; the harness's contiguous
// fills hit 6.6 TB/s on the same allocation). The R4 prefetch fix (+1%)
// falsified the latency theory; in-flight bytes were never the limiter.
//
// Fix: block = (path, u-chunk of 64 rows) x ALL 4096 columns.
//   - thread t owns cols [4t,4t+4) as float4 accumulators -> block streams
//     a CONTIGUOUS 1 MiB slab (16 KiB per row, full row per row-visit).
//   - every thread owns unique output columns -> NO LDS, NO syncthreads,
//     no cross-wave reduction in phase 1. x reads are wave-uniform scalar.
//   - cross-block (u-chunk) reduction via 16 MiB partials in d_ws +
//     a tiny phase-2 sum kernel (coalesced, L2/L3-resident).
// Prediction: p1 ~45-60us @ >5.5 TB/s fetch, p2 ~3-8us, total ~55-75us.

constexpr int MUL = 4096;
constexpr int UC_ROWS = 64;                 // u rows per phase-1 block

// per-path constants (floats):
//   io_off : 0, 4096, 16384, 36864
//   w_off  : 0, 16777216, 33554432, 50331648
//   pbase  : partial-buffer base = cum(64*4096*D) = 0, 262144, 1048576, 2359296
// total partials = 4194304 floats = 16 MiB

// ---------------- phase 1: partial GEMM over a contiguous 1 MiB slab ----
template<int D>
__device__ __forceinline__ void p1body(
    const float* __restrict__ w, const float* __restrict__ x,
    float* __restrict__ part, int io_off, long w_off, long pbase, int uc)
{
  const int t = threadIdx.x;
  // thread's column base: cols [4t, 4t+4)
  const float* __restrict__ wp = w + w_off + (long)uc * (UC_ROWS * (long)MUL) + (t << 2);
  // x slab for this u-chunk: 64*D consecutive floats (wave-uniform reads)
  const float* __restrict__ xg = x + io_off + uc * (UC_ROWS * D);

  float acc[D][4];
  #pragma unroll
  for (int i = 0; i < D; ++i) {
    #pragma unroll
    for (int j = 0; j < 4; ++j) acc[i][j] = 0.f;
  }

  for (int u0 = 0; u0 < UC_ROWS; u0 += 8) {
    float4 wv[8];
    #pragma unroll
    for (int j = 0; j < 8; ++j)          // 8 x 16B in flight per thread
      wv[j] = *reinterpret_cast<const float4*>(wp + (long)(u0 + j) * MUL);
    #pragma unroll
    for (int j = 0; j < 8; ++j) {
      #pragma unroll
      for (int i = 0; i < D; ++i) {
        const float xv = xg[(u0 + j) * D + i];   // uniform -> s_load
        acc[i][0] = fmaf(wv[j].x, xv, acc[i][0]);
        acc[i][1] = fmaf(wv[j].y, xv, acc[i][1]);
        acc[i][2] = fmaf(wv[j].z, xv, acc[i][2]);
        acc[i][3] = fmaf(wv[j].w, xv, acc[i][3]);
      }
    }
  }

  // partial layout: part[pbase + uc*4096*D + v*D + i]; thread covers v=4t..4t+3
  // -> 4*D contiguous floats, 16B-aligned (4*t*D*4 bytes, factor 16).
  alignas(16) float tmp[4 * D];
  #pragma unroll
  for (int j = 0; j < 4; ++j) {
    #pragma unroll
    for (int i = 0; i < D; ++i) tmp[j * D + i] = acc[i][j];
  }
  float4* dst = reinterpret_cast<float4*>(
      part + pbase + (long)uc * (MUL * (long)D) + (long)(t * 4) * D);
  #pragma unroll
  for (int m = 0; m < D; ++m)
    dst[m] = reinterpret_cast<const float4*>(tmp)[m];
}

__global__ __launch_bounds__(1024)
void linear_p1(const float* __restrict__ w, const float* __restrict__ x,
               float* __restrict__ part)
{
  const int b  = blockIdx.x;
  const int p  = b >> 6;          // 64 u-chunks per path
  const int uc = b & 63;
  if      (p == 0) p1body<1>(w, x, part,     0,         0L,       0L, uc);
  else if (p == 1) p1body<3>(w, x, part,  4096,  16777216L,  262144L, uc);
  else if (p == 2) p1body<5>(w, x, part, 16384,  33554432L, 1048576L, uc);
  else             p1body<7>(w, x, part, 36864,  50331648L, 2359296L, uc);
}

// ---------------- phase 2: sum 64 u-chunk partials, scale by 1/64 -------
template<int D>
__device__ __forceinline__ void p2body(
    const float* __restrict__ part, float* __restrict__ out,
    int io_off, long pbase, int oblk)
{
  const int o = oblk * 256 + threadIdx.x;        // [0, 4096*D)
  const float* __restrict__ q = part + pbase + o;
  float s0 = 0.f, s1 = 0.f, s2 = 0.f, s3 = 0.f;
  #pragma unroll
  for (int u = 0; u < 64; u += 4) {
    s0 += q[(long)(u + 0) * (MUL * D)];
    s1 += q[(long)(u + 1) * (MUL * D)];
    s2 += q[(long)(u + 2) * (MUL * D)];
    s3 += q[(long)(u + 3) * (MUL * D)];
  }
  out[io_off + o] = ((s0 + s1) + (s2 + s3)) * 0.015625f;
}

__global__ __launch_bounds__(256)
void linear_p2(const float* __restrict__ part, float* __restrict__ out)
{
  const int b = blockIdx.x;       // 16D blocks per path: cum 16, 64, 144, 256
  if      (b < 16)  p2body<1>(part, out,     0,       0L, b);
  else if (b < 64)  p2body<3>(part, out,  4096,  262144L, b - 16);
  else if (b < 144) p2body<5>(part, out, 16384, 1048576L, b - 64);
  else              p2body<7>(part, out, 36864, 2359296L, b - 144);
}

// ---------------- fallback (ws too small): memset + atomic accumulate ---
template<int D>
__device__ __forceinline__ void p1abody(
    const float* __restrict__ w, const float* __restrict__ x,
    float* __restrict__ out, int io_off, long w_off, int uc)
{
  const int t = threadIdx.x;
  const float* __restrict__ wp = w + w_off + (long)uc * (UC_ROWS * (long)MUL) + (t << 2);
  const float* __restrict__ xg = x + io_off + uc * (UC_ROWS * D);

  float acc[D][4];
  #pragma unroll
  for (int i = 0; i < D; ++i) {
    #pragma unroll
    for (int j = 0; j < 4; ++j) acc[i][j] = 0.f;
  }
  for (int u0 = 0; u0 < UC_ROWS; u0 += 8) {
    float4 wv[8];
    #pragma unroll
    for (int j = 0; j < 8; ++j)
      wv[j] = *reinterpret_cast<const float4*>(wp + (long)(u0 + j) * MUL);
    #pragma unroll
    for (int j = 0; j < 8; ++j) {
      #pragma unroll
      for (int i = 0; i < D; ++i) {
        const float xv = xg[(u0 + j) * D + i];
        acc[i][0] = fmaf(wv[j].x, xv, acc[i][0]);
        acc[i][1] = fmaf(wv[j].y, xv, acc[i][1]);
        acc[i][2] = fmaf(wv[j].z, xv, acc[i][2]);
        acc[i][3] = fmaf(wv[j].w, xv, acc[i][3]);
      }
    }
  }
  #pragma unroll
  for (int j = 0; j < 4; ++j) {
    #pragma unroll
    for (int i = 0; i < D; ++i)
      atomicAdd(out + io_off + (t * 4 + j) * D + i, acc[i][j] * 0.015625f);
  }
}

__global__ __launch_bounds__(1024)
void linear_p1_atomic(const float* __restrict__ w, const float* __restrict__ x,
                      float* __restrict__ out)
{
  const int b  = blockIdx.x;
  const int p  = b >> 6;
  const int uc = b & 63;
  if      (p == 0) p1abody<1>(w, x, out,     0,         0L, uc);
  else if (p == 1) p1abody<3>(w, x, out,  4096,  16777216L, uc);
  else if (p == 2) p1abody<5>(w, x, out, 16384,  33554432L, uc);
  else             p1abody<7>(w, x, out, 36864,  50331648L, uc);
}

// ------------------------------------------------------------------------
extern "C" void kernel_launch(void* const* d_in, const int* in_sizes, int n_in,
                              void* d_out, int out_size, void* d_ws, size_t ws_size,
                              hipStream_t stream) {
  const float* x = (const float*)d_in[0];   // 65536 f32
  const float* w = (const float*)d_in[1];   // 67108864 f32
  const size_t need = 4194304UL * sizeof(float);  // 16 MiB partials
  if (d_ws != nullptr && ws_size >= need) {
    float* part = (float*)d_ws;
    linear_p1<<<256, 1024, 0, stream>>>(w, x, part);
    linear_p2<<<256, 256, 0, stream>>>(part, (float*)d_out);
  } else {
    hipMemsetAsync(d_out, 0, 65536 * sizeof(float), stream);
    linear_p1_atomic<<<256, 1024, 0, stream>>>(w, x, (float*)d_out);
  }
}